// Round 7
// baseline (452.924 us; speedup 1.0000x reference)
//
#include <hip/hip_runtime.h>
#include <hip/hip_bf16.h>
#include <stdint.h>

#define B_SZ 4
#define SEQ 2048
#define DM 1024
#define NH 16
#define DK 64
#define BH (B_SZ * NH)      // 64
#define M_TOT (B_SZ * SEQ)  // 8192

typedef unsigned short u16;
typedef u16 u16x8 __attribute__((ext_vector_type(8)));
typedef __bf16 bf16x8 __attribute__((ext_vector_type(8)));
typedef float f32x4 __attribute__((ext_vector_type(4)));

__device__ __forceinline__ u16 f2bf(float f) {
    union { float f; uint32_t u; } v; v.f = f;
    uint32_t u = v.u;
    return (u16)((u + 0x7FFFu + ((u >> 16) & 1u)) >> 16);
}

// truncating fp32->bf16 (1 op; used only for P in [0,1])
__device__ __forceinline__ u16 f2bf_trunc(float f) {
    union { float f; uint32_t u; } v; v.f = f;
    return (u16)(v.u >> 16);
}

__device__ __forceinline__ f32x4 mfma16(u16x8 a, u16x8 b, f32x4 c) {
    return __builtin_amdgcn_mfma_f32_16x16x32_bf16(
        __builtin_bit_cast(bf16x8, a), __builtin_bit_cast(bf16x8, b), c, 0, 0, 0);
}

// async global->LDS, 16 B per lane; lds dest = wave-uniform base + lane*16
__device__ __forceinline__ void gload16_lds(const void* g, void* l) {
    __builtin_amdgcn_global_load_lds(
        (const __attribute__((address_space(1))) void*)(uintptr_t)g,
        (__attribute__((address_space(3))) void*)(uintptr_t)l, 16, 0, 0);
}

// ---------------- x fp32 -> bf16 ----------------
__global__ void cvt_bf16_kernel(const float* __restrict__ in, u16* __restrict__ out, int n4) {
    int i = blockIdx.x * blockDim.x + threadIdx.x;
    if (i < n4) {
        float4 v = ((const float4*)in)[i];
        ushort4 o;
        o.x = f2bf(v.x); o.y = f2bf(v.y); o.z = f2bf(v.z); o.w = f2bf(v.w);
        ((ushort4*)out)[i] = o;
    }
}

// ---------------- W [K][N] fp32 -> Wt [N][K] bf16 (z = weight index) ----------------
__global__ void transpose_w_kernel(const float* __restrict__ W0, const float* __restrict__ W1,
                                   u16* __restrict__ Wt) {
    __shared__ u16 tile[32][33];
    int bx = blockIdx.x, by = blockIdx.y, z = blockIdx.z;
    const float* W = z ? W1 : W0;
    u16* Wd = Wt + (size_t)z * DM * DM;
    int t = threadIdx.x;
    for (int i = 0; i < 4; i++) {
        int idx = t + i * 256;
        int r = idx >> 5, c = idx & 31;
        tile[r][c] = f2bf(W[(by * 32 + r) * DM + bx * 32 + c]);
    }
    __syncthreads();
    for (int i = 0; i < 4; i++) {
        int idx = t + i * 256;
        int r2 = idx >> 5, c2 = idx & 31;
        Wd[(bx * 32 + r2) * DM + by * 32 + c2] = tile[c2][r2];
    }
}

// ---------------- 128x128x64 bf16 GEMM (m97 recipe), global_load_lds staging ----------------
// MODE 0: bf16 scatter to [bh][s][dk]; n<1024 -> C0 (scaled by scale0), else C1.
// MODE 1: fp32 row-major [M][1024] -> C0.
// MODE 2: bf16 TRANSPOSED scatter to Vt[bh][d][s] -> C0 (fused V transpose).
template <int AFP32, int MODE>
__global__ __launch_bounds__(256, 2) void gemm128(
    const void* __restrict__ Ain, const u16* __restrict__ Bt,
    void* __restrict__ C0p, void* __restrict__ C1p, float scale0) {
    __shared__ u16 As[128][64];
    __shared__ u16 Bs[128][64];
    const int K = DM;
    int m0 = blockIdx.x * 128;
    int n0 = blockIdx.y * 128;
    int tid = threadIdx.x;
    int lane = tid & 63, wave = tid >> 6;
    int quad = lane >> 4, l15 = lane & 15;
    int wm = wave >> 1, wn = wave & 1;

    f32x4 acc[4][4];
    for (int i = 0; i < 4; i++)
        for (int j = 0; j < 4; j++) acc[i][j] = f32x4{0.f, 0.f, 0.f, 0.f};

    int r8 = lane >> 3;        // 0..7
    int c8 = (lane & 7) * 8;   // 0..56 (els)

    for (int k0 = 0; k0 < K; k0 += 64) {
        __syncthreads();
        if (AFP32) {
            const float* A = (const float*)Ain;
            for (int j = 0; j < 4; j++) {
                int slot = tid + j * 256;            // 1024 slots of 8 els
                int r = slot >> 3, c = (slot & 7) * 8;
                const float* g = &A[(size_t)(m0 + r) * K + k0 + c];
                float4 v0 = *(const float4*)g;
                float4 v1 = *(const float4*)(g + 4);
                u16x8 o;
                o[0] = f2bf(v0.x); o[1] = f2bf(v0.y); o[2] = f2bf(v0.z); o[3] = f2bf(v0.w);
                o[4] = f2bf(v1.x); o[5] = f2bf(v1.y); o[6] = f2bf(v1.z); o[7] = f2bf(v1.w);
                *(u16x8*)(&As[r][c]) = o;
            }
        } else {
            const u16* A = (const u16*)Ain;
            const u16* ga = &A[(size_t)(m0 + wave * 32 + r8) * K + k0 + c8];
            for (int j = 0; j < 4; j++)
                gload16_lds(ga + (size_t)(8 * j) * K, &As[wave * 32 + 8 * j][0]);
        }
        {
            const u16* gb = &Bt[(size_t)(n0 + wave * 32 + r8) * K + k0 + c8];
            for (int j = 0; j < 4; j++)
                gload16_lds(gb + (size_t)(8 * j) * K, &Bs[wave * 32 + 8 * j][0]);
        }
        __syncthreads();
        u16x8 af[4][2], bfv[4][2];
        for (int mt = 0; mt < 4; mt++)
            for (int kc = 0; kc < 2; kc++)
                af[mt][kc] = *(const u16x8*)(&As[wm * 64 + mt * 16 + l15][kc * 32 + quad * 8]);
        for (int nt = 0; nt < 4; nt++)
            for (int kc = 0; kc < 2; kc++)
                bfv[nt][kc] = *(const u16x8*)(&Bs[wn * 64 + nt * 16 + l15][kc * 32 + quad * 8]);
        for (int kc = 0; kc < 2; kc++)
            for (int mt = 0; mt < 4; mt++)
                for (int nt = 0; nt < 4; nt++)
                    acc[mt][nt] = mfma16(af[mt][kc], bfv[nt][kc], acc[mt][nt]);
    }

    for (int mt = 0; mt < 4; mt++)
        for (int nt = 0; nt < 4; nt++)
            for (int r = 0; r < 4; r++) {
                int m = m0 + wm * 64 + mt * 16 + quad * 4 + r;
                int n = n0 + wn * 64 + nt * 16 + l15;
                float v = acc[mt][nt][r];
                if (MODE == 0) {
                    v *= (n < 1024) ? scale0 : 1.0f;
                    u16* C = (n < 1024) ? (u16*)C0p : (u16*)C1p;
                    int ne = n & 1023;
                    int b = m >> 11, s = m & 2047;
                    int h = ne >> 6, d = ne & 63;
                    C[(((size_t)(b * NH + h) * SEQ) + s) * DK + d] = f2bf(v);
                } else if (MODE == 1) {
                    ((float*)C0p)[(size_t)m * DM + n] = v;
                } else {  // MODE 2: Vt[bh][d][s]
                    int b = m >> 11, s = m & 2047;
                    int h = n >> 6, d = n & 63;
                    ((u16*)C0p)[(((size_t)(b * NH + h) * DK) + d) * SEQ + s] = f2bf(v);
                }
            }
}

// ---------------- causal flash attention v6: BARRIER-FREE ----------------
// Q pre-scaled by (1/8)*log2(e). K: [bh][s][64]. Vt: [bh][d][s]. Out: [b*SEQ+s][h*64+d] bf16.
// No LDS staging of K/V: fragments load straight from global (L2) into registers,
// so there is NO __syncthreads anywhere — waves run free (m97-plateau workaround).
// Wave owns a 32-row q-strip (2 MFMA subtiles sharing each K/V fragment).
// Strip pairing (s, 63-s) -> exactly 33 k-tiles per wave; 1024 blocks = 4/CU all-resident.
// LDS: per-wave P scratch only (stride 68 -> conflict-free stores).
__global__ __launch_bounds__(256, 4) void attn_kernel(
    const u16* __restrict__ Qb, const u16* __restrict__ Kb,
    const u16* __restrict__ Vtb, u16* __restrict__ AOb) {
    __shared__ u16 Pl[4][32][68];   // 17.4 KB

    int bh = blockIdx.x;  // 0..63 ; XCD = bh%8
    int yy = blockIdx.y;  // 0..15
    int tid = threadIdx.x, lane = tid & 63, wave = tid >> 6;
    int quad = lane >> 4, l15 = lane & 15;
    int b = bh >> 4, h = bh & 15;

    const u16* Qg = Qb + (size_t)bh * SEQ * DK;
    const u16* Kg = Kb + (size_t)bh * SEQ * DK;
    const u16* Vg = Vtb + (size_t)bh * DK * SEQ;
    u16* Pw = &Pl[wave][0][0];

    for (int ph = 0; ph < 2; ph++) {
        int s0 = yy * 4 + wave;
        int strip = ph ? (63 - s0) : s0;
        int q0 = strip * 32;
        int lastkt = strip >> 1;

        // Q fragments for the two 16-row subtiles
        u16x8 aq[2][2];
        for (int m = 0; m < 2; m++)
            for (int kc = 0; kc < 2; kc++)
                aq[m][kc] = *(const u16x8*)(
                    &Qg[(size_t)(q0 + m * 16 + l15) * DK + kc * 32 + quad * 8]);

        float lsum[2][4];
        f32x4 O[2][4];
        for (int m = 0; m < 2; m++)
            for (int r = 0; r < 4; r++) lsum[m][r] = 0.f;
        for (int m = 0; m < 2; m++)
            for (int nt = 0; nt < 4; nt++) O[m][nt] = f32x4{0.f, 0.f, 0.f, 0.f};

        for (int kt = 0; kt <= lastkt; kt++) {
            int k0 = kt * 64;
            bool masked = (kt == lastkt);  // diagonal tile is always the last one

            // K fragments: global -> regs (B-operand, rows = keys)
            u16x8 kf[4][2];
            for (int nt = 0; nt < 4; nt++)
                for (int kc = 0; kc < 2; kc++)
                    kf[nt][kc] = *(const u16x8*)(
                        &Kg[(size_t)(k0 + nt * 16 + l15) * DK + kc * 32 + quad * 8]);

            // S = Q K^T ; P = exp2(S) ; P -> LDS (per-nt to keep sc regs short-lived)
            for (int nt = 0; nt < 4; nt++) {
                for (int m = 0; m < 2; m++) {
                    f32x4 z = f32x4{0.f, 0.f, 0.f, 0.f};
                    z = mfma16(aq[m][0], kf[nt][0], z);
                    z = mfma16(aq[m][1], kf[nt][1], z);
                    if (masked) {
                        for (int r = 0; r < 4; r++) {
                            int qa = q0 + m * 16 + quad * 4 + r;
                            int ka = k0 + nt * 16 + l15;
                            float pv = (ka <= qa) ? exp2f(z[r]) : 0.f;
                            lsum[m][r] += pv;
                            Pw[(size_t)(m * 16 + quad * 4 + r) * 68 + nt * 16 + l15] =
                                f2bf_trunc(pv);
                        }
                    } else {
                        for (int r = 0; r < 4; r++) {
                            float pv = exp2f(z[r]);
                            lsum[m][r] += pv;
                            Pw[(size_t)(m * 16 + quad * 4 + r) * 68 + nt * 16 + l15] =
                                f2bf_trunc(pv);
                        }
                    }
                }
            }

            // V^T fragments: global -> regs (B-operand, rows = d)
            u16x8 vf[4][2];
            for (int nt = 0; nt < 4; nt++)
                for (int kc = 0; kc < 2; kc++)
                    vf[nt][kc] = *(const u16x8*)(
                        &Vg[(size_t)(nt * 16 + l15) * SEQ + k0 + kc * 32 + quad * 8]);

            // P fragments from LDS (same-wave ordering: no barrier needed)
            u16x8 ap[2][2];
            for (int m = 0; m < 2; m++)
                for (int kc = 0; kc < 2; kc++)
                    ap[m][kc] = *(const u16x8*)(
                        &Pw[(size_t)(m * 16 + l15) * 68 + kc * 32 + quad * 8]);

            // O += P V
            for (int nt = 0; nt < 4; nt++)
                for (int m = 0; m < 2; m++) {
                    O[m][nt] = mfma16(ap[m][0], vf[nt][0], O[m][nt]);
                    O[m][nt] = mfma16(ap[m][1], vf[nt][1], O[m][nt]);
                }
        }

        // epilogue: reduce lsum across the 16 column lanes, normalize, store
        for (int m = 0; m < 2; m++)
            for (int r = 0; r < 4; r++) {
                float s = lsum[m][r];
                for (int off = 1; off < 16; off <<= 1) s += __shfl_xor(s, off, 64);
                float inv = 1.0f / s;
                int q = q0 + m * 16 + quad * 4 + r;
                for (int nt = 0; nt < 4; nt++) {
                    int d = nt * 16 + l15;
                    AOb[((size_t)(b * SEQ + q)) * DM + h * DK + d] = f2bf(O[m][nt][r] * inv);
                }
            }
    }
}

extern "C" void kernel_launch(void* const* d_in, const int* in_sizes, int n_in,
                              void* d_out, int out_size, void* d_ws, size_t ws_size,
                              hipStream_t stream) {
    const float* x = (const float*)d_in[0];
    const float* Wq = (const float*)d_in[1];
    const float* Wk = (const float*)d_in[2];
    const float* Wv = (const float*)d_in[3];
    const float* Wo = (const float*)d_in[4];
    float* out = (float*)d_out;

    // Regions: ws = S0|S1 (16 MB each), d_out = D0|D1 (16 MB each).
    // 1. cvt x -> xb@S0
    // 2. T(Wq,Wk) -> wqk@D0 head (4 MB)
    // 3. gemmQK(xb, wqk) -> Q@S1 (scaled), K@D1
    // 4. T(Wv) -> wvt@S0 head (xb dead: V-GEMM reads fp32 x directly)
    // 5. gemmV MODE2 (x fp32, wvt) -> Vt@D0 [bh][d][s]
    // 6. attn(Q@S1, K@D1, Vt@D0) -> AO@S0
    // 7. T(Wo) -> wot@S1 head (Q dead)
    // 8. gemmO(AO@S0, wot@S1h) -> d_out fp32
    const size_t HALF = (size_t)M_TOT * DM * 2;  // 16 MB
    char* S0 = (char*)d_ws;
    char* S1 = (char*)d_ws + HALF;
    char* D0 = (char*)d_out;
    char* D1 = (char*)d_out + HALF;

    u16* xb  = (u16*)S0;
    u16* Qb  = (u16*)S1;
    u16* Kb  = (u16*)D1;
    u16* Vt  = (u16*)D0;
    u16* AOb = (u16*)S0;
    u16* wqk = (u16*)D0;   // 4 MB
    u16* wvt = (u16*)S0;   // 2 MB over dead xb
    u16* wot = (u16*)S1;   // 2 MB over dead Q

    const float cscale = 0.125f * 1.44269504088896f;  // 1/sqrt(64) * log2(e)
    dim3 tg2(32, 32, 2);
    dim3 tg1(32, 32, 1);
    dim3 gg(M_TOT / 128, DM / 128);

    // 1) x -> bf16
    int n4 = M_TOT * DM / 4;
    cvt_bf16_kernel<<<n4 / 256, 256, 0, stream>>>(x, xb, n4);

    // 2-3) fused Q,K projection (Q pre-scaled)
    transpose_w_kernel<<<tg2, 256, 0, stream>>>(Wq, Wk, wqk);
    dim3 gqk(M_TOT / 128, 2048 / 128);
    gemm128<0, 0><<<gqk, 256, 0, stream>>>(xb, wqk, (void*)Qb, (void*)Kb, cscale);

    // 4-5) V projection with fused transpose (fp32 A from d_in)
    transpose_w_kernel<<<tg1, 256, 0, stream>>>(Wv, Wv, wvt);
    gemm128<1, 2><<<gg, 256, 0, stream>>>(x, wvt, (void*)Vt, (void*)Vt, 1.0f);

    // 6) attention (barrier-free)
    dim3 ag(BH, 16);
    attn_kernel<<<ag, 256, 0, stream>>>(Qb, Kb, Vt, AOb);

    // 7-8) output projection straight into d_out
    transpose_w_kernel<<<tg1, 256, 0, stream>>>(Wo, Wo, wot);
    gemm128<0, 1><<<gg, 256, 0, stream>>>(AOb, wot, (void*)out, (void*)out, 1.0f);
}